// Round 1
// baseline (3144.500 us; speedup 1.0000x reference)
//
#include <hip/hip_runtime.h>
#include <hip/hip_bf16.h>
#include <math.h>

// Problem constants
#define BB 4
#define NN 2048
#define DM 1024
#define NH 16
#define DH 64

// ---------------------------------------------------------------------------
// GEMM: C[M,N] = A[M,K] * B[N,K]^T   (both row-major; dot of rows)
// 128x128 tile, BK=8, 256 threads, 8x8 per thread (as 2x2 blocks of 4x4)
// ---------------------------------------------------------------------------
__global__ __launch_bounds__(256) void gemm_nt(const float* __restrict__ A,
                                               const float* __restrict__ Bw,
                                               float* __restrict__ C,
                                               int M, int N, int K) {
  __shared__ float As[8][128];
  __shared__ float Bs[8][128];
  const int t = threadIdx.x;
  const int row0 = blockIdx.y * 128;
  const int col0 = blockIdx.x * 128;
  const int lr = t >> 1;          // 0..127
  const int lk = (t & 1) * 4;     // 0 or 4
  const int tr = (t >> 4) * 4;    // 0..60
  const int tc = (t & 15) * 4;    // 0..60

  float acc[8][8];
  #pragma unroll
  for (int i = 0; i < 8; ++i)
    #pragma unroll
    for (int j = 0; j < 8; ++j) acc[i][j] = 0.f;

  const float* Ap = A + (size_t)(row0 + lr) * K + lk;
  const float* Bp = Bw + (size_t)(col0 + lr) * K + lk;

  for (int k0 = 0; k0 < K; k0 += 8) {
    const float4 av = *(const float4*)(Ap + k0);
    const float4 bv = *(const float4*)(Bp + k0);
    __syncthreads();
    As[lk + 0][lr] = av.x; As[lk + 1][lr] = av.y;
    As[lk + 2][lr] = av.z; As[lk + 3][lr] = av.w;
    Bs[lk + 0][lr] = bv.x; Bs[lk + 1][lr] = bv.y;
    Bs[lk + 2][lr] = bv.z; Bs[lk + 3][lr] = bv.w;
    __syncthreads();
    #pragma unroll
    for (int kk = 0; kk < 8; ++kk) {
      float a[8], b[8];
      *(float4*)&a[0] = *(const float4*)&As[kk][tr];
      *(float4*)&a[4] = *(const float4*)&As[kk][tr + 64];
      *(float4*)&b[0] = *(const float4*)&Bs[kk][tc];
      *(float4*)&b[4] = *(const float4*)&Bs[kk][tc + 64];
      #pragma unroll
      for (int i = 0; i < 8; ++i)
        #pragma unroll
        for (int j = 0; j < 8; ++j) acc[i][j] = fmaf(a[i], b[j], acc[i][j]);
    }
  }
  #pragma unroll
  for (int i = 0; i < 8; ++i) {
    const int row = row0 + ((i < 4) ? (tr + i) : (64 + tr + i - 4));
    float* cp = C + (size_t)row * N + col0;
    float4 s0 = make_float4(acc[i][0], acc[i][1], acc[i][2], acc[i][3]);
    float4 s1 = make_float4(acc[i][4], acc[i][5], acc[i][6], acc[i][7]);
    *(float4*)(cp + tc) = s0;
    *(float4*)(cp + 64 + tc) = s1;
  }
}

// ---------------------------------------------------------------------------
// Row LayerNorm in place: one 256-thread block per row of 1024
// ---------------------------------------------------------------------------
__global__ __launch_bounds__(256) void ln_kernel(float* __restrict__ Y,
                                                 const float* __restrict__ g,
                                                 const float* __restrict__ bb) {
  const int t = threadIdx.x;
  float* y = Y + (size_t)blockIdx.x * DM;
  float4 v = ((const float4*)y)[t];
  __shared__ float red[4];
  float s = v.x + v.y + v.z + v.w;
  #pragma unroll
  for (int off = 1; off < 64; off <<= 1) s += __shfl_xor(s, off, 64);
  if ((t & 63) == 0) red[t >> 6] = s;
  __syncthreads();
  const float mean = (red[0] + red[1] + red[2] + red[3]) * (1.f / 1024.f);
  const float dx = v.x - mean, dy = v.y - mean, dz = v.z - mean, dw = v.w - mean;
  float sq = dx * dx + dy * dy + dz * dz + dw * dw;
  #pragma unroll
  for (int off = 1; off < 64; off <<= 1) sq += __shfl_xor(sq, off, 64);
  __syncthreads();
  if ((t & 63) == 0) red[t >> 6] = sq;
  __syncthreads();
  const float inv = rsqrtf((red[0] + red[1] + red[2] + red[3]) * (1.f / 1024.f) + 1e-5f);
  const float4 gv = ((const float4*)g)[t];
  const float4 bv = ((const float4*)bb)[t];
  float4 o;
  o.x = dx * inv * gv.x + bv.x;
  o.y = dy * inv * gv.y + bv.y;
  o.z = dz * inv * gv.z + bv.z;
  o.w = dw * inv * gv.w + bv.w;
  ((float4*)y)[t] = o;
}

// ---------------------------------------------------------------------------
// F_mask: F[b,n,m] = sum_{i<n} relu(q0_i . k0_m / 8) * [1<=m<i]
// Thread per (b,m); K0 row in regs; Q rows staged through LDS (broadcast reads).
// Grid: 32 blocks of 256 (b = blk>>3, m = (blk&7)*256 + tid)
// ---------------------------------------------------------------------------
__global__ __launch_bounds__(256) void fmask_kernel(const float* __restrict__ Q,
                                                    const float* __restrict__ Kb,
                                                    float* __restrict__ Fm) {
  const int b = blockIdx.x >> 3;
  const int m = ((blockIdx.x & 7) << 8) + threadIdx.x;
  float4 kreg[16];
  {
    const float4* kp = (const float4*)(Kb + ((size_t)b * NN + m) * DM);
    #pragma unroll
    for (int i = 0; i < 16; ++i) kreg[i] = kp[i];
  }
  __shared__ float Qs[64][68];
  float run = 0.f;
  float* Fb = Fm + (size_t)b * NN * NN + m;
  for (int n0 = 0; n0 < NN; n0 += 64) {
    __syncthreads();
    {
      const int row = threadIdx.x >> 2;
      const int c0 = (threadIdx.x & 3) * 16;
      const float4* qp = (const float4*)(Q + ((size_t)b * NN + n0 + row) * DM + c0);
      float4 q0 = qp[0], q1 = qp[1], q2 = qp[2], q3 = qp[3];
      *(float4*)&Qs[row][c0 + 0]  = q0;
      *(float4*)&Qs[row][c0 + 4]  = q1;
      *(float4*)&Qs[row][c0 + 8]  = q2;
      *(float4*)&Qs[row][c0 + 12] = q3;
    }
    __syncthreads();
    for (int nn = 0; nn < 64; ++nn) {
      const int n = n0 + nn;
      Fb[(size_t)n * NN] = run;
      if (m >= 1 && m < n) {
        float dot = 0.f;
        #pragma unroll
        for (int i = 0; i < 16; ++i) {
          const float4 qv = *(const float4*)&Qs[nn][i * 4];
          dot = fmaf(qv.x, kreg[i].x, dot);
          dot = fmaf(qv.y, kreg[i].y, dot);
          dot = fmaf(qv.z, kreg[i].z, dot);
          dot = fmaf(qv.w, kreg[i].w, dot);
        }
        run += fmaxf(dot * 0.125f, 0.f);
      }
    }
  }
}

// ---------------------------------------------------------------------------
// Flash attention with -F bias. Block: 256 thr = 32 q-rows x 8 lanes.
// Lane (r,s): scores for m = s*4..s*4+3; output d-slice s*8..s*8+7.
// Grid: (N/32, H, B)
// ---------------------------------------------------------------------------
__global__ __launch_bounds__(256) void attn_kernel(const float* __restrict__ Q,
                                                   const float* __restrict__ K,
                                                   const float* __restrict__ V,
                                                   const float* __restrict__ F,
                                                   float* __restrict__ O) {
  const int qt = blockIdx.x;
  const int h  = blockIdx.y;
  const int b  = blockIdx.z;
  const int q0 = qt * 32;
  const int t = threadIdx.x;
  const int r = t >> 3;       // 0..31
  const int s = t & 7;        // 0..7

  __shared__ float Ks[32][68];
  __shared__ float Vs[32][68];

  const size_t base = ((size_t)b * NN) * DM + (size_t)h * DH;
  float qreg[64];
  {
    const float4* qp = (const float4*)(Q + base + (size_t)(q0 + r) * DM);
    #pragma unroll
    for (int i = 0; i < 16; ++i) *(float4*)&qreg[i * 4] = qp[i];
  }
  const float* Fr = F + ((size_t)b * NN + (q0 + r)) * NN;

  float o[8] = {0, 0, 0, 0, 0, 0, 0, 0};
  float mmax = -INFINITY, lsum = 0.f;

  const int lm = t >> 3, ld0 = (t & 7) * 8;
  for (int mt = 0; mt <= qt; ++mt) {
    const int m0 = mt * 32;
    __syncthreads();
    {
      const float* Kg = K + base + (size_t)(m0 + lm) * DM + ld0;
      const float* Vg = V + base + (size_t)(m0 + lm) * DM + ld0;
      *(float4*)&Ks[lm][ld0]     = *(const float4*)Kg;
      *(float4*)&Ks[lm][ld0 + 4] = *(const float4*)(Kg + 4);
      *(float4*)&Vs[lm][ld0]     = *(const float4*)Vg;
      *(float4*)&Vs[lm][ld0 + 4] = *(const float4*)(Vg + 4);
    }
    __syncthreads();
    float sc[4];
    #pragma unroll
    for (int j = 0; j < 4; ++j) {
      const int m = s * 4 + j;
      float dot = 0.f;
      #pragma unroll
      for (int d4 = 0; d4 < 16; ++d4) {
        const float4 kv = *(const float4*)&Ks[m][d4 * 4];
        dot = fmaf(qreg[d4 * 4 + 0], kv.x, dot);
        dot = fmaf(qreg[d4 * 4 + 1], kv.y, dot);
        dot = fmaf(qreg[d4 * 4 + 2], kv.z, dot);
        dot = fmaf(qreg[d4 * 4 + 3], kv.w, dot);
      }
      const int gm = m0 + m;
      const float logit = dot * 0.125f - Fr[gm];
      sc[j] = (gm <= q0 + r) ? logit : -INFINITY;
    }
    float tmax = fmaxf(fmaxf(sc[0], sc[1]), fmaxf(sc[2], sc[3]));
    tmax = fmaxf(tmax, __shfl_xor(tmax, 1, 8));
    tmax = fmaxf(tmax, __shfl_xor(tmax, 2, 8));
    tmax = fmaxf(tmax, __shfl_xor(tmax, 4, 8));
    const float newmax = fmaxf(mmax, tmax);
    const float scale = __expf(mmax - newmax);
    float p[4], ts = 0.f;
    #pragma unroll
    for (int j = 0; j < 4; ++j) { p[j] = __expf(sc[j] - newmax); ts += p[j]; }
    ts += __shfl_xor(ts, 1, 8);
    ts += __shfl_xor(ts, 2, 8);
    ts += __shfl_xor(ts, 4, 8);
    lsum = lsum * scale + ts;
    mmax = newmax;
    #pragma unroll
    for (int dd = 0; dd < 8; ++dd) o[dd] *= scale;
    #pragma unroll
    for (int mm = 0; mm < 32; ++mm) {
      const float pv = __shfl(p[mm & 3], mm >> 2, 8);
      const float4 v0 = *(const float4*)&Vs[mm][s * 8];
      const float4 v1 = *(const float4*)&Vs[mm][s * 8 + 4];
      o[0] = fmaf(pv, v0.x, o[0]); o[1] = fmaf(pv, v0.y, o[1]);
      o[2] = fmaf(pv, v0.z, o[2]); o[3] = fmaf(pv, v0.w, o[3]);
      o[4] = fmaf(pv, v1.x, o[4]); o[5] = fmaf(pv, v1.y, o[5]);
      o[6] = fmaf(pv, v1.z, o[6]); o[7] = fmaf(pv, v1.w, o[7]);
    }
  }
  const float invl = 1.0f / lsum;
  float4 o0 = make_float4(o[0] * invl, o[1] * invl, o[2] * invl, o[3] * invl);
  float4 o1 = make_float4(o[4] * invl, o[5] * invl, o[6] * invl, o[7] * invl);
  float* Op = O + base + (size_t)(q0 + r) * DM + s * 8;
  *(float4*)Op = o0;
  *(float4*)(Op + 4) = o1;
}

// ---------------------------------------------------------------------------
extern "C" void kernel_launch(void* const* d_in, const int* in_sizes, int n_in,
                              void* d_out, int out_size, void* d_ws, size_t ws_size,
                              hipStream_t stream) {
  (void)in_sizes; (void)n_in; (void)out_size; (void)ws_size;
  const float* X  = (const float*)d_in[0];
  const float* Wq = (const float*)d_in[1];
  const float* Wk = (const float*)d_in[2];
  const float* Wv = (const float*)d_in[3];
  const float* Wo = (const float*)d_in[4];
  const float* gq = (const float*)d_in[5];
  const float* bq = (const float*)d_in[6];
  const float* gk = (const float*)d_in[7];
  const float* bk = (const float*)d_in[8];
  // d_in[9] = start_pos (unused in use_pruning=False path)

  float* out = (float*)d_out;                       // (B,N,D) = 8,388,608 f32
  float* Fm  = out + (size_t)BB * NN * DM;          // (B,N,N) = 16,777,216 f32

  // workspace: Q,K,V,O each B*N*D f32 = 33.5 MB → 134 MB total
  float* Qw = (float*)d_ws;
  float* Kw = Qw + (size_t)BB * NN * DM;
  float* Vw = Kw + (size_t)BB * NN * DM;
  float* Ow = Vw + (size_t)BB * NN * DM;

  const int M = BB * NN;                            // 8192
  dim3 gg(DM / 128, M / 128);                       // (8, 64)

  gemm_nt<<<gg, 256, 0, stream>>>(X, Wq, Qw, M, DM, DM);
  gemm_nt<<<gg, 256, 0, stream>>>(X, Wk, Kw, M, DM, DM);
  gemm_nt<<<gg, 256, 0, stream>>>(X, Wv, Vw, M, DM, DM);
  ln_kernel<<<M, 256, 0, stream>>>(Qw, gq, bq);
  ln_kernel<<<M, 256, 0, stream>>>(Kw, gk, bk);
  fmask_kernel<<<BB * (NN / 256), 256, 0, stream>>>(Qw, Kw, Fm);
  attn_kernel<<<dim3(NN / 32, NH, BB), 256, 0, stream>>>(Qw, Kw, Vw, Fm, Ow);
  gemm_nt<<<gg, 256, 0, stream>>>(Ow, Wo, out, M, DM, DM);
}

// Round 2
// 2554.880 us; speedup vs baseline: 1.2308x; 1.2308x over previous
//
#include <hip/hip_runtime.h>
#include <hip/hip_bf16.h>
#include <math.h>

// Problem constants
#define BB 4
#define NN 2048
#define DM 1024
#define NH 16
#define DH 64

typedef short short8 __attribute__((ext_vector_type(8)));
typedef float f32x4 __attribute__((ext_vector_type(4)));

static __device__ __forceinline__ unsigned short f2bf(float x) {
  unsigned u = __builtin_bit_cast(unsigned, x);
  u += 0x7fffu + ((u >> 16) & 1u);            // RNE
  return (unsigned short)(u >> 16);
}
static __device__ __forceinline__ float bf2f(short s) {
  return __builtin_bit_cast(float, ((unsigned)(unsigned short)s) << 16);
}

// ---------------------------------------------------------------------------
// GEMM: C[M,N] = A[M,K] * B[N,K]^T   (both row-major; dot of rows)
// ---------------------------------------------------------------------------
__global__ __launch_bounds__(256) void gemm_nt(const float* __restrict__ A,
                                               const float* __restrict__ Bw,
                                               float* __restrict__ C,
                                               int M, int N, int K) {
  __shared__ float As[8][128];
  __shared__ float Bs[8][128];
  const int t = threadIdx.x;
  const int row0 = blockIdx.y * 128;
  const int col0 = blockIdx.x * 128;
  const int lr = t >> 1;
  const int lk = (t & 1) * 4;
  const int tr = (t >> 4) * 4;
  const int tc = (t & 15) * 4;

  float acc[8][8];
  #pragma unroll
  for (int i = 0; i < 8; ++i)
    #pragma unroll
    for (int j = 0; j < 8; ++j) acc[i][j] = 0.f;

  const float* Ap = A + (size_t)(row0 + lr) * K + lk;
  const float* Bp = Bw + (size_t)(col0 + lr) * K + lk;

  for (int k0 = 0; k0 < K; k0 += 8) {
    const float4 av = *(const float4*)(Ap + k0);
    const float4 bv = *(const float4*)(Bp + k0);
    __syncthreads();
    As[lk + 0][lr] = av.x; As[lk + 1][lr] = av.y;
    As[lk + 2][lr] = av.z; As[lk + 3][lr] = av.w;
    Bs[lk + 0][lr] = bv.x; Bs[lk + 1][lr] = bv.y;
    Bs[lk + 2][lr] = bv.z; Bs[lk + 3][lr] = bv.w;
    __syncthreads();
    #pragma unroll
    for (int kk = 0; kk < 8; ++kk) {
      float a[8], b[8];
      *(float4*)&a[0] = *(const float4*)&As[kk][tr];
      *(float4*)&a[4] = *(const float4*)&As[kk][tr + 64];
      *(float4*)&b[0] = *(const float4*)&Bs[kk][tc];
      *(float4*)&b[4] = *(const float4*)&Bs[kk][tc + 64];
      #pragma unroll
      for (int i = 0; i < 8; ++i)
        #pragma unroll
        for (int j = 0; j < 8; ++j) acc[i][j] = fmaf(a[i], b[j], acc[i][j]);
    }
  }
  #pragma unroll
  for (int i = 0; i < 8; ++i) {
    const int row = row0 + ((i < 4) ? (tr + i) : (64 + tr + i - 4));
    float* cp = C + (size_t)row * N + col0;
    *(float4*)(cp + tc)      = make_float4(acc[i][0], acc[i][1], acc[i][2], acc[i][3]);
    *(float4*)(cp + 64 + tc) = make_float4(acc[i][4], acc[i][5], acc[i][6], acc[i][7]);
  }
}

// ---------------------------------------------------------------------------
// GEMM TN: C[M,N] = A^T-stored * B^T. A stored per-batch as [K=1024][2048] f32
// (i.e. OwT layout (b,h,d,q)). M index = b*2048 + q.
// ---------------------------------------------------------------------------
__global__ __launch_bounds__(256) void gemm_tn(const float* __restrict__ AT,
                                               const float* __restrict__ Bw,
                                               float* __restrict__ C,
                                               int N, int K) {
  __shared__ float As[8][128];
  __shared__ float Bs[8][128];
  const int t = threadIdx.x;
  const int row0 = blockIdx.y * 128;
  const int col0 = blockIdx.x * 128;
  const int bidx = row0 >> 11;
  const int q0 = row0 & 2047;
  const int lr = t >> 1;
  const int lk = (t & 1) * 4;
  const int sk = t >> 5;            // 0..7
  const int sq = (t & 31) * 4;      // 0..124
  const int tr = (t >> 4) * 4;
  const int tc = (t & 15) * 4;

  float acc[8][8];
  #pragma unroll
  for (int i = 0; i < 8; ++i)
    #pragma unroll
    for (int j = 0; j < 8; ++j) acc[i][j] = 0.f;

  const float* Ap = AT + (size_t)bidx * DM * NN + (size_t)sk * NN + q0 + sq;
  const float* Bp = Bw + (size_t)(col0 + lr) * K + lk;

  for (int k0 = 0; k0 < K; k0 += 8) {
    const float4 av = *(const float4*)(Ap + (size_t)k0 * NN);
    const float4 bv = *(const float4*)(Bp + k0);
    __syncthreads();
    *(float4*)&As[sk][sq] = av;
    Bs[lk + 0][lr] = bv.x; Bs[lk + 1][lr] = bv.y;
    Bs[lk + 2][lr] = bv.z; Bs[lk + 3][lr] = bv.w;
    __syncthreads();
    #pragma unroll
    for (int kk = 0; kk < 8; ++kk) {
      float a[8], b[8];
      *(float4*)&a[0] = *(const float4*)&As[kk][tr];
      *(float4*)&a[4] = *(const float4*)&As[kk][tr + 64];
      *(float4*)&b[0] = *(const float4*)&Bs[kk][tc];
      *(float4*)&b[4] = *(const float4*)&Bs[kk][tc + 64];
      #pragma unroll
      for (int i = 0; i < 8; ++i)
        #pragma unroll
        for (int j = 0; j < 8; ++j) acc[i][j] = fmaf(a[i], b[j], acc[i][j]);
    }
  }
  #pragma unroll
  for (int i = 0; i < 8; ++i) {
    const int row = row0 + ((i < 4) ? (tr + i) : (64 + tr + i - 4));
    float* cp = C + (size_t)row * N + col0;
    *(float4*)(cp + tc)      = make_float4(acc[i][0], acc[i][1], acc[i][2], acc[i][3]);
    *(float4*)(cp + 64 + tc) = make_float4(acc[i][4], acc[i][5], acc[i][6], acc[i][7]);
  }
}

// ---------------------------------------------------------------------------
// LayerNorm + bf16 pack: (b,n,f) f32 -> (b,h,n,d) bf16
// ---------------------------------------------------------------------------
__global__ __launch_bounds__(256) void ln_pack(const float* __restrict__ Y,
                                               const float* __restrict__ g,
                                               const float* __restrict__ bb,
                                               unsigned short* __restrict__ out) {
  const int t = threadIdx.x;
  const int bidx = blockIdx.x >> 11;
  const int n = blockIdx.x & 2047;
  const float* y = Y + (size_t)blockIdx.x * DM;
  float4 v = ((const float4*)y)[t];
  __shared__ float red[4];
  float s = v.x + v.y + v.z + v.w;
  #pragma unroll
  for (int off = 1; off < 64; off <<= 1) s += __shfl_xor(s, off, 64);
  if ((t & 63) == 0) red[t >> 6] = s;
  __syncthreads();
  const float mean = (red[0] + red[1] + red[2] + red[3]) * (1.f / 1024.f);
  const float dx = v.x - mean, dy = v.y - mean, dz = v.z - mean, dw = v.w - mean;
  float sq = dx * dx + dy * dy + dz * dz + dw * dw;
  #pragma unroll
  for (int off = 1; off < 64; off <<= 1) sq += __shfl_xor(sq, off, 64);
  __syncthreads();
  if ((t & 63) == 0) red[t >> 6] = sq;
  __syncthreads();
  const float inv = rsqrtf((red[0] + red[1] + red[2] + red[3]) * (1.f / 1024.f) + 1e-5f);
  const float4 gv = ((const float4*)g)[t];
  const float4 bv = ((const float4*)bb)[t];
  const float o0 = dx * inv * gv.x + bv.x;
  const float o1 = dy * inv * gv.y + bv.y;
  const float o2 = dz * inv * gv.z + bv.z;
  const float o3 = dw * inv * gv.w + bv.w;
  ushort4 w4;
  w4.x = f2bf(o0); w4.y = f2bf(o1); w4.z = f2bf(o2); w4.w = f2bf(o3);
  unsigned short* dst = out + (((size_t)bidx * NH + (t >> 4)) * NN + n) * DH + (t & 15) * 4;
  *(ushort4*)dst = w4;
}

// ---------------------------------------------------------------------------
// V pack + transpose: (b,n,f) f32 -> Vt (b,h,d,m) bf16
// ---------------------------------------------------------------------------
__global__ __launch_bounds__(256) void vpack(const float* __restrict__ V,
                                             unsigned short* __restrict__ Vt) {
  const int tid = blockIdx.x * 256 + threadIdx.x;
  const int d = tid & 63;
  const int rest = tid >> 6;
  const int m0 = (rest & 255) * 8;
  const int h = (rest >> 8) & 15;
  const int b = rest >> 12;
  const float* src = V + ((size_t)b * NN + m0) * DM + h * DH + d;
  unsigned short tmp[8];
  #pragma unroll
  for (int i = 0; i < 8; ++i) tmp[i] = f2bf(src[(size_t)i * DM]);
  unsigned short* dst = Vt + (((size_t)b * NH + h) * DH + d) * NN + m0;
  *(short8*)dst = *(const short8*)tmp;
}

// ---------------------------------------------------------------------------
// F_mask from bf16 head-0 Q/K: F[b,n,m] = sum_{i<n} relu(q_i.k_m/8)*[1<=m<i]
// ---------------------------------------------------------------------------
__global__ __launch_bounds__(256) void fmask_kernel(const unsigned short* __restrict__ Qh,
                                                    const unsigned short* __restrict__ Kh,
                                                    float* __restrict__ Fm) {
  const int b = blockIdx.x >> 3;
  const int m = ((blockIdx.x & 7) << 8) + threadIdx.x;
  float kr[64];
  {
    const short8* kp = (const short8*)(Kh + ((size_t)b * NH * NN + m) * DH);
    #pragma unroll
    for (int i = 0; i < 8; ++i) {
      short8 kv = kp[i];
      #pragma unroll
      for (int j = 0; j < 8; ++j) kr[i * 8 + j] = bf2f(kv[j]);
    }
  }
  const float4* kv4 = (const float4*)kr;
  __shared__ float Qs[64][68];
  float run = 0.f;
  float* Fb = Fm + (size_t)b * NN * NN + m;
  for (int n0 = 0; n0 < NN; n0 += 64) {
    __syncthreads();
    {
      const int row = threadIdx.x >> 2;
      const int c0 = (threadIdx.x & 3) * 16;
      const short8* qp = (const short8*)(Qh + ((size_t)b * NH * NN + n0 + row) * DH + c0);
      short8 qa = qp[0], qb = qp[1];
      #pragma unroll
      for (int j = 0; j < 8; ++j) {
        Qs[row][c0 + j] = bf2f(qa[j]);
        Qs[row][c0 + 8 + j] = bf2f(qb[j]);
      }
    }
    __syncthreads();
    for (int nn = 0; nn < 64; ++nn) {
      const int n = n0 + nn;
      Fb[(size_t)n * NN] = run;
      if (m >= 1 && m < n) {
        float dot = 0.f;
        #pragma unroll
        for (int i = 0; i < 16; ++i) {
          const float4 qv = *(const float4*)&Qs[nn][i * 4];
          dot = fmaf(qv.x, kv4[i].x, dot);
          dot = fmaf(qv.y, kv4[i].y, dot);
          dot = fmaf(qv.z, kv4[i].z, dot);
          dot = fmaf(qv.w, kv4[i].w, dot);
        }
        run += fmaxf(dot * 0.125f, 0.f);
      }
    }
  }
}

// ---------------------------------------------------------------------------
// MFMA flash attention (swapped QK^T), 1 wave / 16 q-rows, no LDS.
// S^T = K.Q^T via mfma_f32_16x16x32_bf16 with K-row permutation
//   m_abs(t, i) = m0 + 8*(i>>2) + 4t + (i&3)
// so lane (g,c)'s D values land at m = m0 + 8g + (4t+r) == PV B-fragment
// k-index 8g+j. P needs no shuffles/LDS. O^T accumulated via mfma(V^T, P).
// ---------------------------------------------------------------------------
__global__ __launch_bounds__(64) void attn_mfma(const unsigned short* __restrict__ Qh,
                                                const unsigned short* __restrict__ Kh,
                                                const unsigned short* __restrict__ Vt,
                                                const float* __restrict__ F,
                                                float* __restrict__ OwT) {
  const int lane = threadIdx.x;
  const int g = lane >> 4, c = lane & 15;
  const int qt = blockIdx.x;
  const int h = blockIdx.y, b = blockIdx.z;
  const int q0 = qt * 16;
  const size_t bh = (size_t)b * NH + h;

  // Q B-fragments: col q=c, k(d) = g*8 + j (+32 for second half of DH)
  const short8* qp = (const short8*)(Qh + (bh * NN + q0 + c) * DH + g * 8);
  const short8 qf0 = qp[0];
  const short8 qf1 = qp[4];   // +32 shorts

  const int krow = 8 * (c >> 2) + (c & 3);
  const unsigned short* kbase = Kh + (bh * NN + krow) * DH + g * 8;
  const unsigned short* vbase = Vt + (bh * DH + c) * NN + g * 8;
  const float* fbase = F + ((size_t)b * NN + q0 + c) * NN + 8 * g;

  f32x4 o0 = {0.f, 0.f, 0.f, 0.f}, o1 = o0, o2 = o0, o3 = o0;
  float mrun = -INFINITY, lrun = 0.f;
  const int qabs = q0 + c;
  const int ntiles = (qt >> 1) + 1;

  for (int mt = 0; mt < ntiles; ++mt) {
    const int m0 = mt * 32;
    // K A-fragments (permuted rows), accumulate over d-halves
    const unsigned short* kp = kbase + (size_t)m0 * DH;
    short8 k00 = *(const short8*)kp;
    short8 k01 = *(const short8*)(kp + 32);
    short8 k10 = *(const short8*)(kp + 4 * DH);
    short8 k11 = *(const short8*)(kp + 4 * DH + 32);
    f32x4 z = {0.f, 0.f, 0.f, 0.f};
    f32x4 st0 = __builtin_amdgcn_mfma_f32_16x16x32_bf16(k00, qf0, z, 0, 0, 0);
    st0 = __builtin_amdgcn_mfma_f32_16x16x32_bf16(k01, qf1, st0, 0, 0, 0);
    f32x4 st1 = __builtin_amdgcn_mfma_f32_16x16x32_bf16(k10, qf0, z, 0, 0, 0);
    st1 = __builtin_amdgcn_mfma_f32_16x16x32_bf16(k11, qf1, st1, 0, 0, 0);

    // F bias: lane's own q-row, cols m0+8g..+7 (two f32x4, line-perfect)
    f32x4 fa = *(const f32x4*)(fbase + m0);
    f32x4 fb = *(const f32x4*)(fbase + m0 + 4);

    float p[8];
    float tmax = -INFINITY;
    #pragma unroll
    for (int j = 0; j < 8; ++j) {
      const int mrel = 8 * g + j;
      float x = ((j < 4) ? st0[j] : st1[j - 4]) * 0.125f - ((j < 4) ? fa[j] : fb[j - 4]);
      if (m0 + mrel > qabs) x = -INFINITY;
      p[j] = x;
      tmax = fmaxf(tmax, x);
    }
    tmax = fmaxf(tmax, __shfl_xor(tmax, 16, 64));
    tmax = fmaxf(tmax, __shfl_xor(tmax, 32, 64));
    const float nm = fmaxf(mrun, tmax);
    const float sc = __expf(mrun - nm);
    float ts = 0.f;
    #pragma unroll
    for (int j = 0; j < 8; ++j) { p[j] = __expf(p[j] - nm); ts += p[j]; }
    ts += __shfl_xor(ts, 16, 64);
    ts += __shfl_xor(ts, 32, 64);
    lrun = lrun * sc + ts;
    mrun = nm;
    #pragma unroll
    for (int e = 0; e < 4; ++e) { o0[e] *= sc; o1[e] *= sc; o2[e] *= sc; o3[e] *= sc; }

    // pack P into bf16x8 B-fragment (element j <-> k = 8g+j) — lane-local
    union { unsigned u[4]; short8 v; } pf;
    #pragma unroll
    for (int w = 0; w < 4; ++w)
      pf.u[w] = (unsigned)f2bf(p[2 * w]) | ((unsigned)f2bf(p[2 * w + 1]) << 16);

    // V^T A-fragments: row d = dt*16 + c, k -> m0 + 8g + j (contiguous 16B)
    const unsigned short* vp = vbase + m0;
    short8 v0 = *(const short8*)vp;
    short8 v1 = *(const short8*)(vp + 16 * NN);
    short8 v2 = *(const short8*)(vp + 32 * NN);
    short8 v3 = *(const short8*)(vp + 48 * NN);
    o0 = __builtin_amdgcn_mfma_f32_16x16x32_bf16(v0, pf.v, o0, 0, 0, 0);
    o1 = __builtin_amdgcn_mfma_f32_16x16x32_bf16(v1, pf.v, o1, 0, 0, 0);
    o2 = __builtin_amdgcn_mfma_f32_16x16x32_bf16(v2, pf.v, o2, 0, 0, 0);
    o3 = __builtin_amdgcn_mfma_f32_16x16x32_bf16(v3, pf.v, o3, 0, 0, 0);
  }

  const float invl = 1.f / lrun;
  // O^T write: OwT[(bh*DH + dt*16 + 4g + r)*NN + q0 + c]
  float* op = OwT + (bh * DH + 4 * g) * NN + q0 + c;
  #pragma unroll
  for (int r = 0; r < 4; ++r) {
    op[(0 * 16 + r) * NN] = o0[r] * invl;
    op[(1 * 16 + r) * NN] = o1[r] * invl;
    op[(2 * 16 + r) * NN] = o2[r] * invl;
    op[(3 * 16 + r) * NN] = o3[r] * invl;
  }
}

// ---------------------------------------------------------------------------
extern "C" void kernel_launch(void* const* d_in, const int* in_sizes, int n_in,
                              void* d_out, int out_size, void* d_ws, size_t ws_size,
                              hipStream_t stream) {
  (void)in_sizes; (void)n_in; (void)out_size; (void)ws_size;
  const float* X  = (const float*)d_in[0];
  const float* Wq = (const float*)d_in[1];
  const float* Wk = (const float*)d_in[2];
  const float* Wv = (const float*)d_in[3];
  const float* Wo = (const float*)d_in[4];
  const float* gq = (const float*)d_in[5];
  const float* bq = (const float*)d_in[6];
  const float* gk = (const float*)d_in[7];
  const float* bk = (const float*)d_in[8];

  float* out = (float*)d_out;                        // (B,N,D) f32
  float* Fm  = out + (size_t)BB * NN * DM;           // (B,N,N) f32

  // workspace layout (84 MB): one f32 scratch (reused) + 3 bf16 buffers
  float* fbuf = (float*)d_ws;                        // 8.4M f32 (Qw/Kw/Vw/OwT)
  unsigned short* Qh = (unsigned short*)(fbuf + (size_t)BB * NN * DM);
  unsigned short* Kh = Qh + (size_t)BB * NN * DM;
  unsigned short* Vt = Kh + (size_t)BB * NN * DM;

  const int M = BB * NN;                             // 8192
  dim3 gg(DM / 128, M / 128);                        // (8, 64)

  gemm_nt<<<gg, 256, 0, stream>>>(X, Wq, fbuf, M, DM, DM);
  ln_pack<<<M, 256, 0, stream>>>(fbuf, gq, bq, Qh);
  gemm_nt<<<gg, 256, 0, stream>>>(X, Wk, fbuf, M, DM, DM);
  ln_pack<<<M, 256, 0, stream>>>(fbuf, gk, bk, Kh);
  gemm_nt<<<gg, 256, 0, stream>>>(X, Wv, fbuf, M, DM, DM);
  vpack<<<4096, 256, 0, stream>>>(fbuf, Vt);
  fmask_kernel<<<BB * (NN / 256), 256, 0, stream>>>(Qh, Kh, Fm);
  attn_mfma<<<dim3(NN / 16, NH, BB), 64, 0, stream>>>(Qh, Kh, Vt, Fm, fbuf);
  gemm_tn<<<gg, 256, 0, stream>>>(fbuf, Wo, out, DM, DM);
}

// Round 3
// 659.929 us; speedup vs baseline: 4.7649x; 3.8714x over previous
//
#include <hip/hip_runtime.h>
#include <hip/hip_bf16.h>
#include <math.h>

// Problem constants
#define BB 4
#define NN 2048
#define DM 1024
#define NH 16
#define DH 64

typedef short short8 __attribute__((ext_vector_type(8)));
typedef float f32x4 __attribute__((ext_vector_type(4)));

static __device__ __forceinline__ unsigned short f2bf(float x) {
  unsigned u = __builtin_bit_cast(unsigned, x);
  u += 0x7fffu + ((u >> 16) & 1u);            // RNE
  return (unsigned short)(u >> 16);
}
static __device__ __forceinline__ float bf2f(short s) {
  return __builtin_bit_cast(float, ((unsigned)(unsigned short)s) << 16);
}

typedef __attribute__((address_space(1))) const void gv_t;
typedef __attribute__((address_space(3))) void lv_t;
static __device__ __forceinline__ void gload16(const void* gsrc, void* ldst) {
  __builtin_amdgcn_global_load_lds((gv_t*)gsrc, (lv_t*)ldst, 16, 0, 0);
}

// ---------------------------------------------------------------------------
// pack f32 -> bf16, 8 elems/thread
// ---------------------------------------------------------------------------
__global__ __launch_bounds__(256) void pack_bf16(const float* __restrict__ in,
                                                 unsigned short* __restrict__ out,
                                                 int n8) {
  const int i = blockIdx.x * 256 + threadIdx.x;
  if (i >= n8) return;
  const float4* p = (const float4*)in + 2 * (size_t)i;
  const float4 x = p[0], y = p[1];
  unsigned short tmp[8] = {f2bf(x.x), f2bf(x.y), f2bf(x.z), f2bf(x.w),
                           f2bf(y.x), f2bf(y.y), f2bf(y.z), f2bf(y.w)};
  *(short8*)(out + 8 * (size_t)i) = *(const short8*)tmp;
}

// ---------------------------------------------------------------------------
// bf16 MFMA GEMM: C[M,N] f32 = A[M,K] * B[N,K]^T (both bf16 row-major).
// 128x128 tile, BK=32, 4 waves (2x2), 4x4 frags of 16x16x32 per wave.
// global_load_lds width-16 staging into linear LDS [row][k].
// ---------------------------------------------------------------------------
__global__ __launch_bounds__(256) void gemm_bf16(const unsigned short* __restrict__ A,
                                                 const unsigned short* __restrict__ Bw,
                                                 float* __restrict__ C,
                                                 int M, int N, int K) {
  __shared__ unsigned short As[128 * 32];
  __shared__ unsigned short Bs[128 * 32];
  const int t = threadIdx.x;
  const int row0 = blockIdx.y * 128, col0 = blockIdx.x * 128;
  const int lane = t & 63, w = t >> 6;
  const int wr = (w >> 1) * 64, wc = (w & 1) * 64;
  const int g = lane >> 4, c = lane & 15;

  f32x4 acc[4][4];
  #pragma unroll
  for (int i = 0; i < 4; ++i)
    #pragma unroll
    for (int j = 0; j < 4; ++j) acc[i][j] = (f32x4){0.f, 0.f, 0.f, 0.f};

  // staging: lane t covers row=t>>2 (and +64), 16B chunk (t&3)
  const unsigned short* Asrc = A + (size_t)(row0 + (t >> 2)) * K + (t & 3) * 8;
  const unsigned short* Bsrc = Bw + (size_t)(col0 + (t >> 2)) * K + (t & 3) * 8;
  unsigned short* dA0 = &As[t * 8];
  unsigned short* dA1 = &As[2048 + t * 8];
  unsigned short* dB0 = &Bs[t * 8];
  unsigned short* dB1 = &Bs[2048 + t * 8];

  for (int kt = 0; kt < K; kt += 32) {
    __syncthreads();
    gload16(Asrc + kt, dA0);
    gload16(Asrc + (size_t)64 * K + kt, dA1);
    gload16(Bsrc + kt, dB0);
    gload16(Bsrc + (size_t)64 * K + kt, dB1);
    __syncthreads();
    short8 a[4], bf[4];
    #pragma unroll
    for (int i = 0; i < 4; ++i)
      a[i] = *(const short8*)&As[(wr + i * 16 + c) * 32 + g * 8];
    #pragma unroll
    for (int j = 0; j < 4; ++j)
      bf[j] = *(const short8*)&Bs[(wc + j * 16 + c) * 32 + g * 8];
    #pragma unroll
    for (int i = 0; i < 4; ++i)
      #pragma unroll
      for (int j = 0; j < 4; ++j)
        acc[i][j] = __builtin_amdgcn_mfma_f32_16x16x32_bf16(a[i], bf[j], acc[i][j], 0, 0, 0);
  }
  // epilogue: D row = 4g+r, col = c within each 16x16 frag
  #pragma unroll
  for (int i = 0; i < 4; ++i) {
    #pragma unroll
    for (int r = 0; r < 4; ++r) {
      float* cp = C + (size_t)(row0 + wr + i * 16 + 4 * g + r) * N + col0 + wc + c;
      #pragma unroll
      for (int j = 0; j < 4; ++j) cp[j * 16] = acc[i][j][r];
    }
  }
}

// ---------------------------------------------------------------------------
// LayerNorm + bf16 pack: (b,n,f) f32 -> (b,h,n,d) bf16
// ---------------------------------------------------------------------------
__global__ __launch_bounds__(256) void ln_pack(const float* __restrict__ Y,
                                               const float* __restrict__ g,
                                               const float* __restrict__ bb,
                                               unsigned short* __restrict__ out) {
  const int t = threadIdx.x;
  const int bidx = blockIdx.x >> 11;
  const int n = blockIdx.x & 2047;
  const float* y = Y + (size_t)blockIdx.x * DM;
  float4 v = ((const float4*)y)[t];
  __shared__ float red[4];
  float s = v.x + v.y + v.z + v.w;
  #pragma unroll
  for (int off = 1; off < 64; off <<= 1) s += __shfl_xor(s, off, 64);
  if ((t & 63) == 0) red[t >> 6] = s;
  __syncthreads();
  const float mean = (red[0] + red[1] + red[2] + red[3]) * (1.f / 1024.f);
  const float dx = v.x - mean, dy = v.y - mean, dz = v.z - mean, dw = v.w - mean;
  float sq = dx * dx + dy * dy + dz * dz + dw * dw;
  #pragma unroll
  for (int off = 1; off < 64; off <<= 1) sq += __shfl_xor(sq, off, 64);
  __syncthreads();
  if ((t & 63) == 0) red[t >> 6] = sq;
  __syncthreads();
  const float inv = rsqrtf((red[0] + red[1] + red[2] + red[3]) * (1.f / 1024.f) + 1e-5f);
  const float4 gv = ((const float4*)g)[t];
  const float4 bv = ((const float4*)bb)[t];
  ushort4 w4;
  w4.x = f2bf(dx * inv * gv.x + bv.x);
  w4.y = f2bf(dy * inv * gv.y + bv.y);
  w4.z = f2bf(dz * inv * gv.z + bv.z);
  w4.w = f2bf(dw * inv * gv.w + bv.w);
  unsigned short* dst = out + (((size_t)bidx * NH + (t >> 4)) * NN + n) * DH + (t & 15) * 4;
  *(ushort4*)dst = w4;
}

// ---------------------------------------------------------------------------
// V pack + transpose: (b,n,f) f32 -> Vt (b,h,d,m) bf16
// ---------------------------------------------------------------------------
__global__ __launch_bounds__(256) void vpack(const float* __restrict__ V,
                                             unsigned short* __restrict__ Vt) {
  const int tid = blockIdx.x * 256 + threadIdx.x;
  const int d = tid & 63;
  const int rest = tid >> 6;
  const int m0 = (rest & 255) * 8;
  const int h = (rest >> 8) & 15;
  const int b = rest >> 12;
  const float* src = V + ((size_t)b * NN + m0) * DM + h * DH + d;
  unsigned short tmp[8];
  #pragma unroll
  for (int i = 0; i < 8; ++i) tmp[i] = f2bf(src[(size_t)i * DM]);
  unsigned short* dst = Vt + (((size_t)b * NH + h) * DH + d) * NN + m0;
  *(short8*)dst = *(const short8*)tmp;
}

// ---------------------------------------------------------------------------
// F_mask part1: per 64-row tile local prefix + tile sums.
// grid (mc=4, tile=32, b=4); thread owns m0 = mc*512+tid and m1 = m0+256.
// F[b,n,m] (local) = sum_{n0<=i<n} relu(q_i.k_m/8)*[1<=m<i]; BS = tile total.
// ---------------------------------------------------------------------------
__global__ __launch_bounds__(256) void fmask_part1(const unsigned short* __restrict__ Qh,
                                                   const unsigned short* __restrict__ Kh,
                                                   float* __restrict__ Fm,
                                                   float* __restrict__ BS) {
  const int b = blockIdx.z, tl = blockIdx.y;
  const int m0 = blockIdx.x * 512 + threadIdx.x;
  const int m1 = m0 + 256;
  const int n0 = tl * 64;
  float ka[64], kb[64];
  {
    const short8* kp = (const short8*)(Kh + ((size_t)b * NH * NN + m0) * DH);
    const short8* kq = (const short8*)(Kh + ((size_t)b * NH * NN + m1) * DH);
    #pragma unroll
    for (int i = 0; i < 8; ++i) {
      short8 kv = kp[i], kw = kq[i];
      #pragma unroll
      for (int j = 0; j < 8; ++j) { ka[i * 8 + j] = bf2f(kv[j]); kb[i * 8 + j] = bf2f(kw[j]); }
    }
  }
  __shared__ float Qs[64][68];
  {
    const int row = threadIdx.x >> 2;
    const int c0 = (threadIdx.x & 3) * 16;
    const short8* qp = (const short8*)(Qh + ((size_t)b * NH * NN + n0 + row) * DH + c0);
    short8 qa = qp[0], qb = qp[1];
    #pragma unroll
    for (int j = 0; j < 8; ++j) {
      Qs[row][c0 + j] = bf2f(qa[j]);
      Qs[row][c0 + 8 + j] = bf2f(qb[j]);
    }
  }
  __syncthreads();
  const float4* ka4 = (const float4*)ka;
  const float4* kb4 = (const float4*)kb;
  float runa = 0.f, runb = 0.f;
  float* Fa = Fm + (size_t)b * NN * NN + m0;
  float* Fb = Fa + 256;
  for (int nn = 0; nn < 64; ++nn) {
    const int n = n0 + nn;
    Fa[(size_t)n * NN] = runa;
    Fb[(size_t)n * NN] = runb;
    float da = 0.f, db = 0.f;
    #pragma unroll
    for (int i = 0; i < 16; ++i) {
      const float4 qv = *(const float4*)&Qs[nn][i * 4];
      da = fmaf(qv.x, ka4[i].x, da); db = fmaf(qv.x, kb4[i].x, db);
      da = fmaf(qv.y, ka4[i].y, da); db = fmaf(qv.y, kb4[i].y, db);
      da = fmaf(qv.z, ka4[i].z, da); db = fmaf(qv.z, kb4[i].z, db);
      da = fmaf(qv.w, ka4[i].w, da); db = fmaf(qv.w, kb4[i].w, db);
    }
    if (m0 >= 1 && m0 < n) runa += fmaxf(da * 0.125f, 0.f);
    if (m1 < n) runb += fmaxf(db * 0.125f, 0.f);
  }
  BS[((size_t)b * 32 + tl) * NN + m0] = runa;
  BS[((size_t)b * 32 + tl) * NN + m1] = runb;
}

// ---------------------------------------------------------------------------
// F_mask part2: add cross-tile prefix. grid (mc=8, t-1=31, b=4).
// ---------------------------------------------------------------------------
__global__ __launch_bounds__(256) void fmask_part2(const float* __restrict__ BS,
                                                   float* __restrict__ Fm) {
  const int b = blockIdx.z;
  const int tlt = blockIdx.y + 1;  // 1..31
  const int m = blockIdx.x * 256 + threadIdx.x;
  float pre = 0.f;
  const float* bs = BS + (size_t)b * 32 * NN + m;
  for (int t2 = 0; t2 < tlt; ++t2) pre += bs[(size_t)t2 * NN];
  float* Fp = Fm + ((size_t)b * NN + tlt * 64) * NN + m;
  #pragma unroll 4
  for (int nn = 0; nn < 64; ++nn) Fp[(size_t)nn * NN] += pre;
}

// ---------------------------------------------------------------------------
// MFMA flash attention, 4 waves / 64 q-rows per block, K/V LDS-shared.
// K/V tiles staged fragment-major via global_load_lds (perm baked in source):
//   Kf[f][lane][8]: f = (hs<<1)|ds : row = 8*(c>>2)+(c&3)+4*hs, k-d = g*8+32*ds
//   Vf[dt][lane][8]: row d = 16*dt + c, k-m = m0 + 8*g
// Compute per wave identical to verified round-2 lane math.
// ---------------------------------------------------------------------------
__global__ __launch_bounds__(256) void attn_mfma(const unsigned short* __restrict__ Qh,
                                                 const unsigned short* __restrict__ Kh,
                                                 const unsigned short* __restrict__ Vt,
                                                 const float* __restrict__ F,
                                                 unsigned short* __restrict__ Oh) {
  const int t = threadIdx.x, lane = t & 63, w = t >> 6;
  const int g = lane >> 4, c = lane & 15;
  const int bx = blockIdx.x, h = blockIdx.y, b = blockIdx.z;
  const int q0w = bx * 64 + w * 16;
  const size_t bh = (size_t)b * NH + h;

  __shared__ union {
    struct { unsigned short Kf[4][64][8]; unsigned short Vf[4][64][8]; } tl;
    float Ot[4][16][68];
  } sm;

  // Q B-fragments: col q=c, k(d) = g*8+j (+32)
  const short8* qp = (const short8*)(Qh + (bh * NN + q0w + c) * DH + g * 8);
  const short8 qf0 = qp[0];
  const short8 qf1 = qp[4];
  const float* fbase = F + ((size_t)b * NN + q0w + c) * NN + 8 * g;

  // staging sources for this thread's LDS slot (frag = w, stage-lane = lane)
  const int hs = w >> 1, ds = w & 1;
  const int kperm = 8 * (c >> 2) + (c & 3) + 4 * hs;
  const unsigned short* srcK = Kh + (bh * NN + kperm) * DH + g * 8 + 32 * ds;
  const unsigned short* srcV = Vt + (bh * DH + 16 * w + c) * NN + 8 * g;
  unsigned short* dstK = &sm.tl.Kf[0][0][0] + t * 8;
  unsigned short* dstV = &sm.tl.Vf[0][0][0] + t * 8;

  f32x4 o0 = {0.f, 0.f, 0.f, 0.f}, o1 = o0, o2 = o0, o3 = o0;
  float mrun = -INFINITY, lrun = 0.f;
  const int qabs = q0w + c;
  const int qmax = q0w + 15;
  const int ntiles = 2 * bx + 2;

  for (int mt = 0; mt < ntiles; ++mt) {
    const int m0 = mt * 32;
    __syncthreads();
    gload16(srcK + (size_t)m0 * DH, dstK);
    gload16(srcV + m0, dstV);
    __syncthreads();
    if (m0 <= qmax) {
      const short8 k00 = *(const short8*)&sm.tl.Kf[0][lane][0];
      const short8 k01 = *(const short8*)&sm.tl.Kf[1][lane][0];
      const short8 k10 = *(const short8*)&sm.tl.Kf[2][lane][0];
      const short8 k11 = *(const short8*)&sm.tl.Kf[3][lane][0];
      f32x4 z = {0.f, 0.f, 0.f, 0.f};
      f32x4 st0 = __builtin_amdgcn_mfma_f32_16x16x32_bf16(k00, qf0, z, 0, 0, 0);
      st0 = __builtin_amdgcn_mfma_f32_16x16x32_bf16(k01, qf1, st0, 0, 0, 0);
      f32x4 st1 = __builtin_amdgcn_mfma_f32_16x16x32_bf16(k10, qf0, z, 0, 0, 0);
      st1 = __builtin_amdgcn_mfma_f32_16x16x32_bf16(k11, qf1, st1, 0, 0, 0);

      const f32x4 fa = *(const f32x4*)(fbase + m0);
      const f32x4 fb = *(const f32x4*)(fbase + m0 + 4);

      float p[8];
      float tmax = -INFINITY;
      #pragma unroll
      for (int j = 0; j < 8; ++j) {
        const int mrel = 8 * g + j;
        float x = ((j < 4) ? st0[j] : st1[j - 4]) * 0.125f - ((j < 4) ? fa[j] : fb[j - 4]);
        if (m0 + mrel > qabs) x = -INFINITY;
        p[j] = x;
        tmax = fmaxf(tmax, x);
      }
      tmax = fmaxf(tmax, __shfl_xor(tmax, 16, 64));
      tmax = fmaxf(tmax, __shfl_xor(tmax, 32, 64));
      const float nm = fmaxf(mrun, tmax);
      const float sc = __expf(mrun - nm);
      float ts = 0.f;
      #pragma unroll
      for (int j = 0; j < 8; ++j) { p[j] = __expf(p[j] - nm); ts += p[j]; }
      ts += __shfl_xor(ts, 16, 64);
      ts += __shfl_xor(ts, 32, 64);
      lrun = lrun * sc + ts;
      mrun = nm;
      #pragma unroll
      for (int e = 0; e < 4; ++e) { o0[e] *= sc; o1[e] *= sc; o2[e] *= sc; o3[e] *= sc; }

      union { unsigned u[4]; short8 v; } pf;
      #pragma unroll
      for (int q = 0; q < 4; ++q)
        pf.u[q] = (unsigned)f2bf(p[2 * q]) | ((unsigned)f2bf(p[2 * q + 1]) << 16);

      const short8 v0 = *(const short8*)&sm.tl.Vf[0][lane][0];
      const short8 v1 = *(const short8*)&sm.tl.Vf[1][lane][0];
      const short8 v2 = *(const short8*)&sm.tl.Vf[2][lane][0];
      const short8 v3 = *(const short8*)&sm.tl.Vf[3][lane][0];
      o0 = __builtin_amdgcn_mfma_f32_16x16x32_bf16(v0, pf.v, o0, 0, 0, 0);
      o1 = __builtin_amdgcn_mfma_f32_16x16x32_bf16(v1, pf.v, o1, 0, 0, 0);
      o2 = __builtin_amdgcn_mfma_f32_16x16x32_bf16(v2, pf.v, o2, 0, 0, 0);
      o3 = __builtin_amdgcn_mfma_f32_16x16x32_bf16(v3, pf.v, o3, 0, 0, 0);
    }
  }

  // epilogue: transpose via LDS, write Oh (b,n,f) bf16 coalesced
  __syncthreads();
  const float invl = 1.f / lrun;
  #pragma unroll
  for (int r = 0; r < 4; ++r) {
    sm.Ot[w][c][0 * 16 + 4 * g + r] = o0[r] * invl;
    sm.Ot[w][c][1 * 16 + 4 * g + r] = o1[r] * invl;
    sm.Ot[w][c][2 * 16 + 4 * g + r] = o2[r] * invl;
    sm.Ot[w][c][3 * 16 + 4 * g + r] = o3[r] * invl;
  }
  __syncthreads();
  {
    const int q = lane >> 2, d0 = (lane & 3) * 16;
    unsigned short tmp[16];
    #pragma unroll
    for (int i = 0; i < 16; ++i) tmp[i] = f2bf(sm.Ot[w][q][d0 + i]);
    unsigned short* dst = Oh + ((size_t)b * NN + q0w + q) * DM + h * DH + d0;
    *(short8*)dst = *(const short8*)&tmp[0];
    *(short8*)(dst + 8) = *(const short8*)&tmp[8];
  }
}

// ---------------------------------------------------------------------------
extern "C" void kernel_launch(void* const* d_in, const int* in_sizes, int n_in,
                              void* d_out, int out_size, void* d_ws, size_t ws_size,
                              hipStream_t stream) {
  (void)in_sizes; (void)n_in; (void)out_size; (void)ws_size;
  const float* X  = (const float*)d_in[0];
  const float* Wq = (const float*)d_in[1];
  const float* Wk = (const float*)d_in[2];
  const float* Wv = (const float*)d_in[3];
  const float* Wo = (const float*)d_in[4];
  const float* gq = (const float*)d_in[5];
  const float* bq = (const float*)d_in[6];
  const float* gk = (const float*)d_in[7];
  const float* bk = (const float*)d_in[8];

  float* out = (float*)d_out;                        // (B,N,D) f32
  float* Fm  = out + (size_t)BB * NN * DM;           // (B,N,N) f32

  const size_t E = (size_t)BB * NN * DM;             // 8388608
  float* fbuf = (float*)d_ws;                        // f32 scratch (gemm out)
  unsigned short* Xh = (unsigned short*)(fbuf + E);
  unsigned short* Qh = Xh + E;
  unsigned short* Kh = Qh + E;
  unsigned short* Vt = Kh + E;
  unsigned short* Oh = Vt + E;
  unsigned short* Wh = Oh + E;                       // 4 x 1M bf16 weights
  float* BS = (float*)(Wh + 4 * 1048576);            // (B,32,NN) f32 tile sums

  const int M = BB * NN;                             // 8192
  dim3 gg(DM / 128, M / 128);                        // (8, 64)

  pack_bf16<<<4096, 256, 0, stream>>>(X, Xh, 1048576);
  pack_bf16<<<512, 256, 0, stream>>>(Wq, Wh + 0 * 1048576, 131072);
  pack_bf16<<<512, 256, 0, stream>>>(Wk, Wh + 1 * 1048576, 131072);
  pack_bf16<<<512, 256, 0, stream>>>(Wv, Wh + 2 * 1048576, 131072);
  pack_bf16<<<512, 256, 0, stream>>>(Wo, Wh + 3 * 1048576, 131072);

  gemm_bf16<<<gg, 256, 0, stream>>>(Xh, Wh + 0 * 1048576, fbuf, M, DM, DM);
  ln_pack<<<M, 256, 0, stream>>>(fbuf, gq, bq, Qh);
  gemm_bf16<<<gg, 256, 0, stream>>>(Xh, Wh + 1 * 1048576, fbuf, M, DM, DM);
  ln_pack<<<M, 256, 0, stream>>>(fbuf, gk, bk, Kh);
  gemm_bf16<<<gg, 256, 0, stream>>>(Xh, Wh + 2 * 1048576, fbuf, M, DM, DM);
  vpack<<<4096, 256, 0, stream>>>(fbuf, Vt);

  fmask_part1<<<dim3(4, 32, 4), 256, 0, stream>>>(Qh, Kh, Fm, BS);
  fmask_part2<<<dim3(8, 31, 4), 256, 0, stream>>>(BS, Fm);

  attn_mfma<<<dim3(NN / 64, NH, BB), 256, 0, stream>>>(Qh, Kh, Vt, Fm, Oh);
  gemm_bf16<<<gg, 256, 0, stream>>>(Oh, Wh + 3 * 1048576, out, M, DM, DM);
}

// Round 5
// 493.508 us; speedup vs baseline: 6.3717x; 1.3372x over previous
//
#include <hip/hip_runtime.h>
#include <hip/hip_bf16.h>
#include <math.h>

// Problem constants
#define BB 4
#define NN 2048
#define DM 1024
#define NH 16
#define DH 64

typedef short short8 __attribute__((ext_vector_type(8)));
typedef float f32x4 __attribute__((ext_vector_type(4)));

static __device__ __forceinline__ unsigned short f2bf(float x) {
  unsigned u = __builtin_bit_cast(unsigned, x);
  u += 0x7fffu + ((u >> 16) & 1u);            // RNE
  return (unsigned short)(u >> 16);
}
static __device__ __forceinline__ float bf2f(short s) {
  return __builtin_bit_cast(float, ((unsigned)(unsigned short)s) << 16);
}

typedef __attribute__((address_space(1))) const void gv_t;
typedef __attribute__((address_space(3))) void lv_t;
static __device__ __forceinline__ void gload16(const void* gsrc, void* ldst) {
  __builtin_amdgcn_global_load_lds((gv_t*)gsrc, (lv_t*)ldst, 16, 0, 0);
}

// ---------------------------------------------------------------------------
// pack f32 -> bf16, 8 elems/thread
// ---------------------------------------------------------------------------
__global__ __launch_bounds__(256) void pack_bf16(const float* __restrict__ in,
                                                 unsigned short* __restrict__ out,
                                                 int n8) {
  const int i = blockIdx.x * 256 + threadIdx.x;
  if (i >= n8) return;
  const float4* p = (const float4*)in + 2 * (size_t)i;
  const float4 x = p[0], y = p[1];
  unsigned short tmp[8] = {f2bf(x.x), f2bf(x.y), f2bf(x.z), f2bf(x.w),
                           f2bf(y.x), f2bf(y.y), f2bf(y.z), f2bf(y.w)};
  *(short8*)(out + 8 * (size_t)i) = *(const short8*)tmp;
}

// ---------------------------------------------------------------------------
// bf16 MFMA GEMM: C[M,N] f32 = A[M,K] * B[N,K]^T (both bf16 row-major).
// 128x128 tile, BK=32, 4 waves (2x2), 4x4 frags of 16x16x32 per wave.
// ---------------------------------------------------------------------------
__global__ __launch_bounds__(256) void gemm_bf16(const unsigned short* __restrict__ A,
                                                 const unsigned short* __restrict__ Bw,
                                                 float* __restrict__ C,
                                                 int M, int N, int K) {
  __shared__ unsigned short As[128 * 32];
  __shared__ unsigned short Bs[128 * 32];
  const int t = threadIdx.x;
  const int row0 = blockIdx.y * 128, col0 = blockIdx.x * 128;
  const int lane = t & 63, w = t >> 6;
  const int wr = (w >> 1) * 64, wc = (w & 1) * 64;
  const int g = lane >> 4, c = lane & 15;

  f32x4 acc[4][4];
  #pragma unroll
  for (int i = 0; i < 4; ++i)
    #pragma unroll
    for (int j = 0; j < 4; ++j) acc[i][j] = (f32x4){0.f, 0.f, 0.f, 0.f};

  const unsigned short* Asrc = A + (size_t)(row0 + (t >> 2)) * K + (t & 3) * 8;
  const unsigned short* Bsrc = Bw + (size_t)(col0 + (t >> 2)) * K + (t & 3) * 8;
  unsigned short* dA0 = &As[t * 8];
  unsigned short* dA1 = &As[2048 + t * 8];
  unsigned short* dB0 = &Bs[t * 8];
  unsigned short* dB1 = &Bs[2048 + t * 8];

  for (int kt = 0; kt < K; kt += 32) {
    __syncthreads();
    gload16(Asrc + kt, dA0);
    gload16(Asrc + (size_t)64 * K + kt, dA1);
    gload16(Bsrc + kt, dB0);
    gload16(Bsrc + (size_t)64 * K + kt, dB1);
    __syncthreads();
    short8 a[4], bf[4];
    #pragma unroll
    for (int i = 0; i < 4; ++i)
      a[i] = *(const short8*)&As[(wr + i * 16 + c) * 32 + g * 8];
    #pragma unroll
    for (int j = 0; j < 4; ++j)
      bf[j] = *(const short8*)&Bs[(wc + j * 16 + c) * 32 + g * 8];
    #pragma unroll
    for (int i = 0; i < 4; ++i)
      #pragma unroll
      for (int j = 0; j < 4; ++j)
        acc[i][j] = __builtin_amdgcn_mfma_f32_16x16x32_bf16(a[i], bf[j], acc[i][j], 0, 0, 0);
  }
  #pragma unroll
  for (int i = 0; i < 4; ++i) {
    #pragma unroll
    for (int r = 0; r < 4; ++r) {
      float* cp = C + (size_t)(row0 + wr + i * 16 + 4 * g + r) * N + col0 + wc + c;
      #pragma unroll
      for (int j = 0; j < 4; ++j) cp[j * 16] = acc[i][j][r];
    }
  }
}

// ---------------------------------------------------------------------------
// LayerNorm + bf16 pack: row of 1024 f32 (stride ldy) -> (b,h,n,d) bf16
// ---------------------------------------------------------------------------
__global__ __launch_bounds__(256) void ln_pack(const float* __restrict__ Y, int ldy,
                                               const float* __restrict__ g,
                                               const float* __restrict__ bb,
                                               unsigned short* __restrict__ out) {
  const int t = threadIdx.x;
  const int bidx = blockIdx.x >> 11;
  const int n = blockIdx.x & 2047;
  const float* y = Y + (size_t)blockIdx.x * ldy;
  float4 v = ((const float4*)y)[t];
  __shared__ float red[4];
  float s = v.x + v.y + v.z + v.w;
  #pragma unroll
  for (int off = 1; off < 64; off <<= 1) s += __shfl_xor(s, off, 64);
  if ((t & 63) == 0) red[t >> 6] = s;
  __syncthreads();
  const float mean = (red[0] + red[1] + red[2] + red[3]) * (1.f / 1024.f);
  const float dx = v.x - mean, dy = v.y - mean, dz = v.z - mean, dw = v.w - mean;
  float sq = dx * dx + dy * dy + dz * dz + dw * dw;
  #pragma unroll
  for (int off = 1; off < 64; off <<= 1) sq += __shfl_xor(sq, off, 64);
  __syncthreads();
  if ((t & 63) == 0) red[t >> 6] = sq;
  __syncthreads();
  const float inv = rsqrtf((red[0] + red[1] + red[2] + red[3]) * (1.f / 1024.f) + 1e-5f);
  const float4 gv = ((const float4*)g)[t];
  const float4 bv = ((const float4*)bb)[t];
  ushort4 w4;
  w4.x = f2bf(dx * inv * gv.x + bv.x);
  w4.y = f2bf(dy * inv * gv.y + bv.y);
  w4.z = f2bf(dz * inv * gv.z + bv.z);
  w4.w = f2bf(dw * inv * gv.w + bv.w);
  unsigned short* dst = out + (((size_t)bidx * NH + (t >> 4)) * NN + n) * DH + (t & 15) * 4;
  *(ushort4*)dst = w4;
}

// ---------------------------------------------------------------------------
// V pack + transpose: (b,n,f) f32 -> Vt (b,h,d,m) bf16
// ---------------------------------------------------------------------------
__global__ __launch_bounds__(256) void vpack(const float* __restrict__ V,
                                             unsigned short* __restrict__ Vt) {
  const int tid = blockIdx.x * 256 + threadIdx.x;
  const int d = tid & 63;
  const int rest = tid >> 6;
  const int m0 = (rest & 255) * 8;
  const int h = (rest >> 8) & 15;
  const int b = rest >> 12;
  const float* src = V + ((size_t)b * NN + m0) * DM + h * DH + d;
  unsigned short tmp[8];
  #pragma unroll
  for (int i = 0; i < 8; ++i) tmp[i] = f2bf(src[(size_t)i * DM]);
  unsigned short* dst = Vt + (((size_t)b * NH + h) * DH + d) * NN + m0;
  *(short8*)dst = *(const short8*)tmp;
}

// ---------------------------------------------------------------------------
// F_mask part1: per 64-row tile local prefix + tile sums.
// ---------------------------------------------------------------------------
__global__ __launch_bounds__(256) void fmask_part1(const unsigned short* __restrict__ Qh,
                                                   const unsigned short* __restrict__ Kh,
                                                   float* __restrict__ Fm,
                                                   float* __restrict__ BS) {
  const int b = blockIdx.z, tl = blockIdx.y;
  const int m0 = blockIdx.x * 512 + threadIdx.x;
  const int m1 = m0 + 256;
  const int n0 = tl * 64;
  float ka[64], kb[64];
  {
    const short8* kp = (const short8*)(Kh + ((size_t)b * NH * NN + m0) * DH);
    const short8* kq = (const short8*)(Kh + ((size_t)b * NH * NN + m1) * DH);
    #pragma unroll
    for (int i = 0; i < 8; ++i) {
      short8 kv = kp[i], kw = kq[i];
      #pragma unroll
      for (int j = 0; j < 8; ++j) { ka[i * 8 + j] = bf2f(kv[j]); kb[i * 8 + j] = bf2f(kw[j]); }
    }
  }
  __shared__ float Qs[64][68];
  {
    const int row = threadIdx.x >> 2;
    const int c0 = (threadIdx.x & 3) * 16;
    const short8* qp = (const short8*)(Qh + ((size_t)b * NH * NN + n0 + row) * DH + c0);
    short8 qa = qp[0], qb2 = qp[1];
    #pragma unroll
    for (int j = 0; j < 8; ++j) {
      Qs[row][c0 + j] = bf2f(qa[j]);
      Qs[row][c0 + 8 + j] = bf2f(qb2[j]);
    }
  }
  __syncthreads();
  const float4* ka4 = (const float4*)ka;
  const float4* kb4 = (const float4*)kb;
  float runa = 0.f, runb = 0.f;
  float* Fa = Fm + (size_t)b * NN * NN + m0;
  float* Fb = Fa + 256;
  for (int nn = 0; nn < 64; ++nn) {
    const int n = n0 + nn;
    Fa[(size_t)n * NN] = runa;
    Fb[(size_t)n * NN] = runb;
    float da = 0.f, db = 0.f;
    #pragma unroll
    for (int i = 0; i < 16; ++i) {
      const float4 qv = *(const float4*)&Qs[nn][i * 4];
      da = fmaf(qv.x, ka4[i].x, da); db = fmaf(qv.x, kb4[i].x, db);
      da = fmaf(qv.y, ka4[i].y, da); db = fmaf(qv.y, kb4[i].y, db);
      da = fmaf(qv.z, ka4[i].z, da); db = fmaf(qv.z, kb4[i].z, db);
      da = fmaf(qv.w, ka4[i].w, da); db = fmaf(qv.w, kb4[i].w, db);
    }
    if (m0 >= 1 && m0 < n) runa += fmaxf(da * 0.125f, 0.f);
    if (m1 < n) runb += fmaxf(db * 0.125f, 0.f);
  }
  BS[((size_t)b * 32 + tl) * NN + m0] = runa;
  BS[((size_t)b * 32 + tl) * NN + m1] = runb;
}

// ---------------------------------------------------------------------------
// F_mask part2: add cross-tile prefix. grid (mc=8, t-1=31, b=4).
// ---------------------------------------------------------------------------
__global__ __launch_bounds__(256) void fmask_part2(const float* __restrict__ BS,
                                                   float* __restrict__ Fm) {
  const int b = blockIdx.z;
  const int tlt = blockIdx.y + 1;  // 1..31
  const int m = blockIdx.x * 256 + threadIdx.x;
  float pre = 0.f;
  const float* bs = BS + (size_t)b * 32 * NN + m;
  for (int t2 = 0; t2 < tlt; ++t2) pre += bs[(size_t)t2 * NN];
  float* Fp = Fm + ((size_t)b * NN + tlt * 64) * NN + m;
  #pragma unroll 4
  for (int nn = 0; nn < 64; ++nn) Fp[(size_t)nn * NN] += pre;
}

// ---------------------------------------------------------------------------
// MFMA flash attention v2: 4 waves / 64 q-rows, 64-m tiles, double-buffered
// LDS staging (2-phase counted pipeline), causal pair load-balancing:
// block bx processes q-blocks {bx, 31-bx} sequentially (33 tiles total).
// K frag f = s*4+h*2+ds: row = m0+32s+perm(c)+4h, col = g*8+32ds.
// V frag f = kh*4+dt:   row = 16dt+c,            col = m0+32kh+8g.
// Lane math identical to HW-verified round-2/3 kernel.
// ---------------------------------------------------------------------------
__global__ __launch_bounds__(256) void attn_mfma(const unsigned short* __restrict__ Qh,
                                                 const unsigned short* __restrict__ Kh,
                                                 const unsigned short* __restrict__ Vt,
                                                 const float* __restrict__ F,
                                                 unsigned short* __restrict__ Oh) {
  const int t = threadIdx.x, lane = t & 63, w = t >> 6;
  const int g = lane >> 4, c = lane & 15;
  const int bx = blockIdx.x, h = blockIdx.y, b = blockIdx.z;
  const size_t bh = (size_t)b * NH + h;

  __shared__ union {
    struct { unsigned short Kf[2][8][64][8]; unsigned short Vf[2][8][64][8]; } tl;
    float Ot[4][16][68];
  } sm;

  const int perm = 8 * (c >> 2) + (c & 3);
  // staging: thread stages frag w and w+4 at slot `lane` (dst = uniform + lane*16B)
  const int kr1 = 32 * (w >> 2) + perm + 4 * ((w >> 1) & 1);   // w<4 -> s=0
  const unsigned short* srcK1 = Kh + (bh * NN + kr1) * DH + g * 8 + 32 * (w & 1);
  const unsigned short* srcK2 = srcK1 + (size_t)32 * DH;       // frag w+4 (s=1)
  const unsigned short* srcV1 = Vt + (bh * DH + 16 * w + c) * NN + 8 * g;
  const unsigned short* srcV2 = srcV1 + 32;                    // kh=1
  unsigned short* kdst = &sm.tl.Kf[0][w][lane][0];
  unsigned short* vdst = &sm.tl.Vf[0][w][lane][0];

#define STAGE(buf, mt_) do {                                   \
    const size_t mo_ = (size_t)(mt_) * 64;                     \
    gload16(srcK1 + mo_ * DH, kdst + (buf) * 4096);            \
    gload16(srcK2 + mo_ * DH, kdst + (buf) * 4096 + 2048);     \
    gload16(srcV1 + mo_, vdst + (buf) * 4096);                 \
    gload16(srcV2 + mo_, vdst + (buf) * 4096 + 2048);          \
  } while (0)

  #pragma unroll 1
  for (int p = 0; p < 2; ++p) {
    const int qb = p ? (31 - bx) : bx;
    const int q0w = qb * 64 + w * 16;
    const int qabs = q0w + c;
    const short8* qp = (const short8*)(Qh + (bh * NN + qabs) * DH + g * 8);
    const short8 qf0 = qp[0];
    const short8 qf1 = qp[4];
    const float* fbase = F + ((size_t)b * NN + qabs) * NN + 8 * g;
    f32x4 o0 = {0.f, 0.f, 0.f, 0.f}, o1 = o0, o2 = o0, o3 = o0;
    float mrun = -INFINITY, lrun = 0.f;
    const int nt = qb + 1;

    __builtin_amdgcn_s_barrier();          // protect LDS reuse across pair halves
    STAGE(0, 0);
    asm volatile("s_waitcnt vmcnt(0)" ::: "memory");
    __builtin_amdgcn_s_barrier();

    #pragma unroll 1
    for (int mt = 0; mt < nt; ++mt) {
      const int m0 = mt * 64;
      const int cur = mt & 1;
      if (mt + 1 < nt) STAGE(cur ^ 1, mt + 1);

      // F bias for this lane's q-row, both 32-m subtiles
      const f32x4 f0a = *(const f32x4*)(fbase + m0);
      const f32x4 f0b = *(const f32x4*)(fbase + m0 + 4);
      const f32x4 f1a = *(const f32x4*)(fbase + m0 + 32);
      const f32x4 f1b = *(const f32x4*)(fbase + m0 + 36);

      const unsigned short* kbL = &sm.tl.Kf[cur][0][lane][0];
      f32x4 z = {0.f, 0.f, 0.f, 0.f};
      __builtin_amdgcn_s_setprio(1);
      f32x4 st00 = __builtin_amdgcn_mfma_f32_16x16x32_bf16(*(const short8*)(kbL + 0 * 512), qf0, z, 0, 0, 0);
      st00 = __builtin_amdgcn_mfma_f32_16x16x32_bf16(*(const short8*)(kbL + 1 * 512), qf1, st00, 0, 0, 0);
      f32x4 st01 = __builtin_amdgcn_mfma_f32_16x16x32_bf16(*(const short8*)(kbL + 2 * 512), qf0, z, 0, 0, 0);
      st01 = __builtin_amdgcn_mfma_f32_16x16x32_bf16(*(const short8*)(kbL + 3 * 512), qf1, st01, 0, 0, 0);
      f32x4 st10 = __builtin_amdgcn_mfma_f32_16x16x32_bf16(*(const short8*)(kbL + 4 * 512), qf0, z, 0, 0, 0);
      st10 = __builtin_amdgcn_mfma_f32_16x16x32_bf16(*(const short8*)(kbL + 5 * 512), qf1, st10, 0, 0, 0);
      f32x4 st11 = __builtin_amdgcn_mfma_f32_16x16x32_bf16(*(const short8*)(kbL + 6 * 512), qf0, z, 0, 0, 0);
      st11 = __builtin_amdgcn_mfma_f32_16x16x32_bf16(*(const short8*)(kbL + 7 * 512), qf1, st11, 0, 0, 0);
      __builtin_amdgcn_s_setprio(0);

      float pp[16];
      float tmax = -INFINITY;
      #pragma unroll
      for (int j = 0; j < 8; ++j) {
        const int mr0 = 8 * g + j;
        float x0 = fmaf((j < 4) ? st00[j] : st01[j - 4], 0.125f, -((j < 4) ? f0a[j] : f0b[j - 4]));
        float x1 = fmaf((j < 4) ? st10[j] : st11[j - 4], 0.125f, -((j < 4) ? f1a[j] : f1b[j - 4]));
        if (m0 + mr0 > qabs) x0 = -INFINITY;
        if (m0 + 32 + mr0 > qabs) x1 = -INFINITY;
        pp[j] = x0; pp[8 + j] = x1;
        tmax = fmaxf(tmax, fmaxf(x0, x1));
      }
      tmax = fmaxf(tmax, __shfl_xor(tmax, 16, 64));
      tmax = fmaxf(tmax, __shfl_xor(tmax, 32, 64));
      const float nm = fmaxf(mrun, tmax);
      const float sc = __expf(mrun - nm);
      float ts = 0.f;
      #pragma unroll
      for (int j = 0; j < 16; ++j) { pp[j] = __expf(pp[j] - nm); ts += pp[j]; }
      ts += __shfl_xor(ts, 16, 64);
      ts += __shfl_xor(ts, 32, 64);
      lrun = lrun * sc + ts;
      mrun = nm;
      #pragma unroll
      for (int e = 0; e < 4; ++e) { o0[e] *= sc; o1[e] *= sc; o2[e] *= sc; o3[e] *= sc; }

      union { unsigned u[4]; short8 v; } pf0, pf1;
      #pragma unroll
      for (int q2 = 0; q2 < 4; ++q2) {
        pf0.u[q2] = (unsigned)f2bf(pp[2 * q2]) | ((unsigned)f2bf(pp[2 * q2 + 1]) << 16);
        pf1.u[q2] = (unsigned)f2bf(pp[8 + 2 * q2]) | ((unsigned)f2bf(pp[8 + 2 * q2 + 1]) << 16);
      }

      const unsigned short* vbL = &sm.tl.Vf[cur][0][lane][0];
      __builtin_amdgcn_s_setprio(1);
      o0 = __builtin_amdgcn_mfma_f32_16x16x32_bf16(*(const short8*)(vbL + 0 * 512), pf0.v, o0, 0, 0, 0);
      o1 = __builtin_amdgcn_mfma_f32_16x16x32_bf16(*(const short8*)(vbL + 1 * 512), pf0.v, o1, 0, 0, 0);
      o2 = __builtin_amdgcn_mfma_f32_16x16x32_bf16(*(const short8*)(vbL + 2 * 512), pf0.v, o2, 0, 0, 0);
      o3 = __builtin_amdgcn_mfma_f32_16x16x32_bf16(*(const short8*)(vbL + 3 * 512), pf0.v, o3, 0, 0, 0);
      o0 = __builtin_amdgcn_mfma_f32_16x16x32_bf16(*(const short8*)(vbL + 4 * 512), pf1.v, o0, 0, 0, 0);
      o1 = __builtin_amdgcn_mfma_f32_16x16x32_bf16(*(const short8*)(vbL + 5 * 512), pf1.v, o1, 0, 0, 0);
      o2 = __builtin_amdgcn_mfma_f32_16x16x32_bf16(*(const short8*)(vbL + 6 * 512), pf1.v, o2, 0, 0, 0);
      o3 = __builtin_amdgcn_mfma_f32_16x16x32_bf16(*(const short8*)(vbL + 7 * 512), pf1.v, o3, 0, 0, 0);
      __builtin_amdgcn_s_setprio(0);

      asm volatile("s_waitcnt vmcnt(0)" ::: "memory");
      __builtin_amdgcn_s_barrier();
    }

    // epilogue: transpose via LDS, write Oh (b,n,f) bf16 coalesced
    const float invl = 1.f / lrun;
    #pragma unroll
    for (int r = 0; r < 4; ++r) {
      sm.Ot[w][c][0 * 16 + 4 * g + r] = o0[r] * invl;
      sm.Ot[w][c][1 * 16 + 4 * g + r] = o1[r] * invl;
      sm.Ot[w][c][2 * 16 + 4 * g + r] = o2[r] * invl;
      sm.Ot[w][c][3 * 16 + 4 * g + r] = o3[r] * invl;
    }
    __syncthreads();
    {
      const int q2 = lane >> 2, d0 = (lane & 3) * 16;
      unsigned short tmp[16];
      #pragma unroll
      for (int i = 0; i < 16; ++i) tmp[i] = f2bf(sm.Ot[w][q2][d0 + i]);
      unsigned short* dst = Oh + ((size_t)b * NN + q0w + q2) * DM + h * DH + d0;
      *(short8*)dst = *(const short8*)&tmp[0];
      *(short8*)(dst + 8) = *(const short8*)&tmp[8];
    }
    __syncthreads();
  }
#undef STAGE
}

// ---------------------------------------------------------------------------
extern "C" void kernel_launch(void* const* d_in, const int* in_sizes, int n_in,
                              void* d_out, int out_size, void* d_ws, size_t ws_size,
                              hipStream_t stream) {
  (void)in_sizes; (void)n_in; (void)out_size; (void)ws_size;
  const float* X  = (const float*)d_in[0];
  const float* Wq = (const float*)d_in[1];
  const float* Wk = (const float*)d_in[2];
  const float* Wv = (const float*)d_in[3];
  const float* Wo = (const float*)d_in[4];
  const float* gq = (const float*)d_in[5];
  const float* bq = (const float*)d_in[6];
  const float* gk = (const float*)d_in[7];
  const float* bk = (const float*)d_in[8];

  float* out = (float*)d_out;                        // (B,N,D) f32
  float* Fm  = out + (size_t)BB * NN * DM;           // (B,N,N) f32

  const size_t E = (size_t)BB * NN * DM;             // 8388608
  // ws layout (~127 MB):
  //  fbuf: 8192x2048 f32 (67MB) — phase A: fused QK gemm out; phase B: V f32
  //        in bytes [0,33.5MB) + Vt bf16 at bytes [33.5MB,50.3MB)
  float* fbuf = (float*)d_ws;
  unsigned short* Vt = (unsigned short*)(fbuf + E);  // inside fbuf region
  unsigned short* Xh = (unsigned short*)(fbuf + 2 * E);  // also reused as Oh
  unsigned short* Qh = Xh + E;
  unsigned short* Kh = Qh + E;
  unsigned short* Wh = Kh + E;                       // 4 x 1M bf16 weights
  float* BS = (float*)(Wh + 4 * 1048576);            // (B,32,NN) f32 tile sums
  unsigned short* Oh = Xh;

  const int M = BB * NN;                             // 8192

  pack_bf16<<<4096, 256, 0, stream>>>(X, Xh, 1048576);
  pack_bf16<<<512, 256, 0, stream>>>(Wq, Wh + 0 * 1048576, 131072);
  pack_bf16<<<512, 256, 0, stream>>>(Wk, Wh + 1 * 1048576, 131072);
  pack_bf16<<<512, 256, 0, stream>>>(Wv, Wh + 2 * 1048576, 131072);
  pack_bf16<<<512, 256, 0, stream>>>(Wo, Wh + 3 * 1048576, 131072);

  // fused Q|K projection: C[8192][2048] f32
  gemm_bf16<<<dim3(16, 64), 256, 0, stream>>>(Xh, Wh, fbuf, M, 2048, DM);
  ln_pack<<<M, 256, 0, stream>>>(fbuf, 2048, gq, bq, Qh);
  ln_pack<<<M, 256, 0, stream>>>(fbuf + 1024, 2048, gk, bk, Kh);

  // V projection into fbuf bytes [0,33.5MB), then transpose-pack to Vt
  gemm_bf16<<<dim3(8, 64), 256, 0, stream>>>(Xh, Wh + 2 * 1048576, fbuf, M, DM, DM);
  vpack<<<4096, 256, 0, stream>>>(fbuf, Vt);

  fmask_part1<<<dim3(4, 32, 4), 256, 0, stream>>>(Qh, Kh, Fm, BS);
  fmask_part2<<<dim3(8, 31, 4), 256, 0, stream>>>(BS, Fm);

  attn_mfma<<<dim3(16, NH, BB), 256, 0, stream>>>(Qh, Kh, Vt, Fm, Oh);
  gemm_bf16<<<dim3(8, 64), 256, 0, stream>>>(Oh, Wh + 3 * 1048576, out, M, DM, DM);
}